// Round 1
// baseline (652.616 us; speedup 1.0000x reference)
//
#include <hip/hip_runtime.h>
#include <hip/hip_bf16.h>

#define T_TOTAL 262144
#define B_SEG   4096
#define F_DIM   128
#define H_DIM   256
#define C_DIM   512

typedef __attribute__((ext_vector_type(8))) short short8;
typedef __attribute__((ext_vector_type(4))) float f32x4;

__device__ __forceinline__ short f2bf(float x) {
    __hip_bfloat16 h = __float2bfloat16(x);
    return *reinterpret_cast<short*>(&h);
}
__device__ __forceinline__ float bf2f(short s) {
    unsigned u = ((unsigned)(unsigned short)s) << 16;
    return __uint_as_float(u);
}

// ---------------------------------------------------------------------------
// Kernel 1: convert W1,W2,W3 (fp32, [K][N]) -> bf16 transposed [N][K]
// ---------------------------------------------------------------------------
__global__ __launch_bounds__(256) void convert_weights(
    const float* __restrict__ W1, const float* __restrict__ W2,
    const float* __restrict__ W3,
    short* __restrict__ W1T, short* __restrict__ W2T, short* __restrict__ W3T) {
    int gid = blockIdx.x * 256 + threadIdx.x;
    if (gid < 32768) {                       // W1T: [256][128]
        int n = gid >> 7, k = gid & 127;
        W1T[gid] = f2bf(W1[k * 256 + n]);
    } else if (gid < 32768 + 65536) {        // W2T: [256][256]
        int id = gid - 32768;
        int n = id >> 8, k = id & 255;
        W2T[id] = f2bf(W2[k * 256 + n]);
    } else {                                 // W3T: [512][256]
        int id = gid - 98304;
        int n = id >> 8, k = id & 255;
        W3T[id] = f2bf(W3[k * 512 + n]);
    }
}

// ---------------------------------------------------------------------------
// Kernel 2: q = context @ Wq + bq   (fp32, [4096][256]); 16 rows per block
// ---------------------------------------------------------------------------
__global__ __launch_bounds__(256) void q_kernel(
    const float* __restrict__ context, const float* __restrict__ Wq,
    const float* __restrict__ bq, float* __restrict__ qout) {
    __shared__ float ctx[16][512];
    const int tid = threadIdx.x;
    const int b0 = blockIdx.x * 16;
    const float4* src = reinterpret_cast<const float4*>(context + (size_t)b0 * 512);
    float4* dst = reinterpret_cast<float4*>(&ctx[0][0]);
    for (int i = tid; i < 2048; i += 256) dst[i] = src[i];
    __syncthreads();
    float acc[16];
    float bias = bq[tid];
#pragma unroll
    for (int r = 0; r < 16; r++) acc[r] = bias;
    for (int c = 0; c < 512; c++) {
        float w = Wq[c * 256 + tid];          // coalesced across threads
#pragma unroll
        for (int r = 0; r < 16; r++) acc[r] += ctx[r][c] * w;  // LDS broadcast
    }
#pragma unroll
    for (int r = 0; r < 16; r++) qout[(size_t)(b0 + r) * 256 + tid] = acc[r];
}

// ---------------------------------------------------------------------------
// Kernel 3: fused MLP + logits + v.  M-tile = 64 rows, 8 waves, Nw = 32/wave.
// LDS layout (bf16, XOR-swizzled kgroups, no padding -> 2x32KB exactly):
//   element (row, k) stored at row*K + sg*8 + (k&7),
//   sg = (kgrp & ~15) | ((kgrp ^ (row&15)) & 15),  kgrp = k>>3
// MFMA 16x16x32 bf16 lane maps (m89/m91-verified):
//   A: m = lane&15, k = (lane>>4)*8 + j
//   B: n = lane&15, k = (lane>>4)*8 + j      (we store W^T[n][k] -> contiguous)
//   D: row = (lane>>4)*4 + r, col = lane&15
// ---------------------------------------------------------------------------
template <int K>
__device__ __forceinline__ void run_layer(
    const short* __restrict__ Abuf, const short* __restrict__ WT,
    f32x4 acc[4][2], int l16, int quad, int nb) {
    const f32x4 zero = {0.f, 0.f, 0.f, 0.f};
#pragma unroll
    for (int i = 0; i < 4; i++)
#pragma unroll
        for (int j = 0; j < 2; j++) acc[i][j] = zero;
#pragma unroll
    for (int kk = 0; kk < K / 32; kk++) {
        int kgrp = kk * 4 + quad;
        int sg = (kgrp & ~15) | ((kgrp ^ l16) & 15);
        short8 a[4];
#pragma unroll
        for (int ms = 0; ms < 4; ms++) {
            int m = ms * 16 + l16;
            a[ms] = *reinterpret_cast<const short8*>(&Abuf[m * K + sg * 8]);
        }
        short8 b[2];
#pragma unroll
        for (int ns = 0; ns < 2; ns++) {
            int n = nb + ns * 16 + l16;
            b[ns] = *reinterpret_cast<const short8*>(&WT[n * K + kk * 32 + quad * 8]);
        }
#pragma unroll
        for (int ms = 0; ms < 4; ms++)
#pragma unroll
            for (int ns = 0; ns < 2; ns++)
                acc[ms][ns] = __builtin_amdgcn_mfma_f32_16x16x32_bf16(
                    a[ms], b[ns], acc[ms][ns], 0, 0, 0);
    }
}

__global__ __launch_bounds__(512, 2) void mlp_kernel(
    const float* __restrict__ objects, const int* __restrict__ seg_ids,
    const short* __restrict__ W1T, const short* __restrict__ W2T,
    const short* __restrict__ W3T,
    const float* __restrict__ b1, const float* __restrict__ b2,
    const float* __restrict__ b3,
    const float* __restrict__ qbuf, float* __restrict__ logits_out,
    short* __restrict__ vout) {
    __shared__ __align__(16) short bufA[64 * 256];   // h1, then logit slots, then v-stage
    __shared__ __align__(16) short bufB[64 * 256];   // X (first 16KB), then h2

    const int tid  = threadIdx.x;
    const int wave = tid >> 6;
    const int lane = tid & 63;
    const int quad = lane >> 4;
    const int l16  = lane & 15;
    const int row0 = blockIdx.x * 64;
    const int nb   = wave * 32;

    // ---- stage X: objects[row0:row0+64][0:128] fp32 -> bf16 swizzled in bufB
    {
        const float4* op = reinterpret_cast<const float4*>(objects + (size_t)row0 * 128);
#pragma unroll
        for (int i = 0; i < 2; i++) {
            int u = tid + i * 512;           // 0..1023: m = u>>4, g = u&15
            int m = u >> 4, g = u & 15;
            float4 x0 = op[u * 2];
            float4 x1 = op[u * 2 + 1];
            short8 s;
            s[0] = f2bf(x0.x); s[1] = f2bf(x0.y); s[2] = f2bf(x0.z); s[3] = f2bf(x0.w);
            s[4] = f2bf(x1.x); s[5] = f2bf(x1.y); s[6] = f2bf(x1.z); s[7] = f2bf(x1.w);
            int sg = g ^ (m & 15);
            *reinterpret_cast<short8*>(&bufB[m * 128 + sg * 8]) = s;
        }
    }
    __syncthreads();

    f32x4 acc[4][2];

    // epilogue helper: bias + relu -> bf16 swizzled store
    auto store_relu = [&](short* dstbuf, const float* bias) {
#pragma unroll
        for (int ns = 0; ns < 2; ns++) {
            int col = nb + ns * 16 + l16;
            float bv = bias[col];
            int kgrp = col >> 3;
#pragma unroll
            for (int ms = 0; ms < 4; ms++) {
#pragma unroll
                for (int r = 0; r < 4; r++) {
                    int row = ms * 16 + quad * 4 + r;
                    float v = acc[ms][ns][r] + bv;
                    v = v > 0.f ? v : 0.f;
                    int sg = (kgrp & 16) | ((kgrp ^ (row & 15)) & 15);
                    dstbuf[row * 256 + sg * 8 + (col & 7)] = f2bf(v);
                }
            }
        }
    };

    // ---- layer 1: h1 = relu(X @ W1 + b1)   [64,128]x[128,256] -> bufA
    run_layer<128>(bufB, W1T, acc, l16, quad, nb);
    store_relu(bufA, b1);
    __syncthreads();

    // ---- layer 2: h2 = relu(h1 @ W2 + b2)  [64,256]x[256,256] -> bufB
    run_layer<256>(bufA, W2T, acc, l16, quad, nb);
    store_relu(bufB, b2);
    __syncthreads();

    // ---- layer 3 k-half: k = h2 @ W3[:, :256] + b3[:256]; logits = k . q[seg] / 16
    run_layer<256>(bufB, W3T, acc, l16, quad, nb);
    {
        float* slots = reinterpret_cast<float*>(bufA);   // [8 waves][64 rows]
        float bk0 = b3[nb + l16];
        float bk1 = b3[nb + 16 + l16];
#pragma unroll
        for (int ms = 0; ms < 4; ms++) {
#pragma unroll
            for (int r = 0; r < 4; r++) {
                int row = ms * 16 + quad * 4 + r;
                int seg = seg_ids[row0 + row];
                const float* qrow = qbuf + (size_t)seg * 256;
                float p = (acc[ms][0][r] + bk0) * qrow[nb + l16]
                        + (acc[ms][1][r] + bk1) * qrow[nb + 16 + l16];
                p += __shfl_xor(p, 1);
                p += __shfl_xor(p, 2);
                p += __shfl_xor(p, 4);
                p += __shfl_xor(p, 8);
                if (l16 == 0) slots[wave * 64 + row] = p;
            }
        }
    }
    __syncthreads();
    if (tid < 64) {
        const float* slots = reinterpret_cast<const float*>(bufA);
        float s = 0.f;
#pragma unroll
        for (int wv = 0; wv < 8; wv++) s += slots[wv * 64 + tid];
        logits_out[row0 + tid] = s * 0.0625f;   // / sqrt(256)
    }
    __syncthreads();

    // ---- layer 3 v-half: v = h2 @ W3[:, 256:] + b3[256:]  -> bufA linear -> global
    run_layer<256>(bufB, W3T + 256 * 256, acc, l16, quad, nb);
    {
        float bv0 = b3[256 + nb + l16];
        float bv1 = b3[256 + nb + 16 + l16];
#pragma unroll
        for (int ns = 0; ns < 2; ns++) {
            float bb = ns ? bv1 : bv0;
            int col = nb + ns * 16 + l16;
#pragma unroll
            for (int ms = 0; ms < 4; ms++) {
#pragma unroll
                for (int r = 0; r < 4; r++) {
                    int row = ms * 16 + quad * 4 + r;
                    bufA[row * 256 + col] = f2bf(acc[ms][ns][r] + bb);
                }
            }
        }
    }
    __syncthreads();
    {
        const short8* s8 = reinterpret_cast<const short8*>(bufA);
        short8* g8 = reinterpret_cast<short8*>(vout + (size_t)row0 * 256);
        for (int i = tid; i < 2048; i += 512) g8[i] = s8[i];
    }
}

// ---------------------------------------------------------------------------
// Kernel 4: per-segment softmax + weighted sum of v
// ---------------------------------------------------------------------------
__global__ __launch_bounds__(256) void segment_kernel(
    const float* __restrict__ logits, const short* __restrict__ vbuf,
    const int* __restrict__ seg_ids, float* __restrict__ emb,
    float* __restrict__ wout) {
    const int b = blockIdx.x;
    const int tid = threadIdx.x;
    __shared__ int range[2];
    __shared__ float wred[4];

    if (tid < 2) {
        int target = b + tid;
        int lo = 0, hi = T_TOTAL;
        while (lo < hi) {
            int mid = (lo + hi) >> 1;
            if (seg_ids[mid] < target) lo = mid + 1; else hi = mid;
        }
        range[tid] = lo;
    }
    __syncthreads();
    const int start = range[0], end = range[1];

    // max
    float m = -1e30f;
    for (int t = start + tid; t < end; t += 256) m = fmaxf(m, logits[t]);
#pragma unroll
    for (int off = 32; off >= 1; off >>= 1) m = fmaxf(m, __shfl_xor(m, off));
    if ((tid & 63) == 0) wred[tid >> 6] = m;
    __syncthreads();
    m = fmaxf(fmaxf(wred[0], wred[1]), fmaxf(wred[2], wred[3]));
    __syncthreads();

    // sum of exp
    float s = 0.f;
    for (int t = start + tid; t < end; t += 256) s += __expf(logits[t] - m);
#pragma unroll
    for (int off = 32; off >= 1; off >>= 1) s += __shfl_xor(s, off);
    if ((tid & 63) == 0) wred[tid >> 6] = s;
    __syncthreads();
    float z = wred[0] + wred[1] + wred[2] + wred[3];
    float invz = 1.f / z;

    // write w
    for (int t = start + tid; t < end; t += 256)
        wout[t] = __expf(logits[t] - m) * invz;

    // embedding: thread tid owns column tid
    float acc = 0.f;
    for (int t = start; t < end; t++) {
        float wv = __expf(logits[t] - m) * invz;     // logits[t] broadcast load
        acc += wv * bf2f(vbuf[(size_t)t * 256 + tid]);
    }
    emb[(size_t)b * 256 + tid] = acc;
}

// ---------------------------------------------------------------------------
extern "C" void kernel_launch(void* const* d_in, const int* in_sizes, int n_in,
                              void* d_out, int out_size, void* d_ws, size_t ws_size,
                              hipStream_t stream) {
    const float* objects = (const float*)d_in[0];
    const float* context = (const float*)d_in[1];
    const int*   seg     = (const int*)d_in[2];
    const float* W1 = (const float*)d_in[3];
    const float* b1 = (const float*)d_in[4];
    const float* W2 = (const float*)d_in[5];
    const float* b2 = (const float*)d_in[6];
    const float* W3 = (const float*)d_in[7];
    const float* b3 = (const float*)d_in[8];
    const float* Wq = (const float*)d_in[9];
    const float* bq = (const float*)d_in[10];

    char* ws = (char*)d_ws;
    float* qbuf   = (float*)(ws);                                  // 4 MB
    short* W1T    = (short*)(ws + 4194304);                        // 64 KB
    short* W2T    = (short*)(ws + 4194304 + 65536);                // 128 KB
    short* W3T    = (short*)(ws + 4194304 + 65536 + 131072);       // 256 KB
    float* logits = (float*)(ws + 4194304 + 65536 + 131072 + 262144);          // 1 MB
    short* vbuf   = (short*)(ws + 4194304 + 65536 + 131072 + 262144 + 1048576); // 128 MB

    float* emb  = (float*)d_out;
    float* wout = emb + (size_t)B_SEG * H_DIM;

    convert_weights<<<896, 256, 0, stream>>>(W1, W2, W3, W1T, W2T, W3T);
    q_kernel<<<B_SEG / 16, 256, 0, stream>>>(context, Wq, bq, qbuf);
    mlp_kernel<<<T_TOTAL / 64, 512, 0, stream>>>(objects, seg, W1T, W2T, W3T,
                                                 b1, b2, b3, qbuf, logits, vbuf);
    segment_kernel<<<B_SEG, 256, 0, stream>>>(logits, vbuf, seg, emb, wout);
}

// Round 2
// 577.471 us; speedup vs baseline: 1.1301x; 1.1301x over previous
//
#include <hip/hip_runtime.h>
#include <hip/hip_bf16.h>

#define T_TOTAL 262144
#define B_SEG   4096
#define F_DIM   128
#define H_DIM   256
#define C_DIM   512

typedef __attribute__((ext_vector_type(8))) short short8;
typedef __attribute__((ext_vector_type(4))) float f32x4;

__device__ __forceinline__ short f2bf(float x) {
    __hip_bfloat16 h = __float2bfloat16(x);
    return *reinterpret_cast<short*>(&h);
}
__device__ __forceinline__ float bf2f(short s) {
    unsigned u = ((unsigned)(unsigned short)s) << 16;
    return __uint_as_float(u);
}

// ---------------------------------------------------------------------------
// Kernel 1: convert W1,W2,W3 (fp32, [K][N]) -> bf16 transposed [N][K]
// ---------------------------------------------------------------------------
__global__ __launch_bounds__(256) void convert_weights(
    const float* __restrict__ W1, const float* __restrict__ W2,
    const float* __restrict__ W3,
    short* __restrict__ W1T, short* __restrict__ W2T, short* __restrict__ W3T) {
    int gid = blockIdx.x * 256 + threadIdx.x;
    if (gid < 32768) {                       // W1T: [256][128]
        int n = gid >> 7, k = gid & 127;
        W1T[gid] = f2bf(W1[k * 256 + n]);
    } else if (gid < 32768 + 65536) {        // W2T: [256][256]
        int id = gid - 32768;
        int n = id >> 8, k = id & 255;
        W2T[id] = f2bf(W2[k * 256 + n]);
    } else {                                 // W3T: [512][256]
        int id = gid - 98304;
        int n = id >> 8, k = id & 255;
        W3T[id] = f2bf(W3[k * 512 + n]);
    }
}

// ---------------------------------------------------------------------------
// Kernel 2: q = context @ Wq + bq   (fp32, [4096][256]); 16 rows per block
// ---------------------------------------------------------------------------
__global__ __launch_bounds__(256) void q_kernel(
    const float* __restrict__ context, const float* __restrict__ Wq,
    const float* __restrict__ bq, float* __restrict__ qout) {
    __shared__ float ctx[16][512];
    const int tid = threadIdx.x;
    const int b0 = blockIdx.x * 16;
    const float4* src = reinterpret_cast<const float4*>(context + (size_t)b0 * 512);
    float4* dst = reinterpret_cast<float4*>(&ctx[0][0]);
    for (int i = tid; i < 2048; i += 256) dst[i] = src[i];
    __syncthreads();
    float acc[16];
    float bias = bq[tid];
#pragma unroll
    for (int r = 0; r < 16; r++) acc[r] = bias;
    for (int c = 0; c < 512; c += 4) {
        float w0 = Wq[(c + 0) * 256 + tid];
        float w1 = Wq[(c + 1) * 256 + tid];
        float w2 = Wq[(c + 2) * 256 + tid];
        float w3 = Wq[(c + 3) * 256 + tid];
#pragma unroll
        for (int r = 0; r < 16; r++) {
            float4 cv = *reinterpret_cast<const float4*>(&ctx[r][c]);
            acc[r] += cv.x * w0 + cv.y * w1 + cv.z * w2 + cv.w * w3;
        }
    }
#pragma unroll
    for (int r = 0; r < 16; r++) qout[(size_t)(b0 + r) * 256 + tid] = acc[r];
}

// ---------------------------------------------------------------------------
// Kernel 3: fused MLP. M-tile = 128 rows, block = 512 thr = 8 waves,
// wave grid 2(M)x4(N): each wave owns 64 rows x 64 cols.
// Weights (bf16 W^T[n][k]) live in a depth-2 register ring (A-operand).
// Activations in LDS, XOR-swizzled: elem (m,k) at m*K + ((k>>3)^(m&SM))*8 + (k&7).
// MFMA operand swap: D = W_frag x act_frag -> D[row=n=quad*4+r][col=m=l16],
// so each lane holds 4 CONSECUTIVE n per (ms,ns) => packed short4 stores.
// All fragment layouts identical to the round-1 verified ones.
// ---------------------------------------------------------------------------
template <int K>
__device__ __forceinline__ void run_layer(
    const short* __restrict__ act, const short* __restrict__ Wt,
    int mbase, int nbase, int l16, int quad, f32x4 acc[4][4]) {
    constexpr int KK = K / 32;
    constexpr int SM = (K == 128) ? 15 : 31;
    const f32x4 zero = {0.f, 0.f, 0.f, 0.f};
#pragma unroll
    for (int i = 0; i < 4; i++)
#pragma unroll
        for (int j = 0; j < 4; j++) acc[i][j] = zero;

    short8 wreg[2][4], areg[2][4];
    int arow[4], wrow[4];
#pragma unroll
    for (int ms = 0; ms < 4; ms++) arow[ms] = mbase + ms * 16 + l16;
#pragma unroll
    for (int ns = 0; ns < 4; ns++) wrow[ns] = nbase + ns * 16 + l16;

    auto loadA = [&](int kk, int slot) {
#pragma unroll
        for (int ms = 0; ms < 4; ms++) {
            int m = arow[ms];
            int sg = (kk * 4 + quad) ^ (m & SM);
            areg[slot][ms] = *reinterpret_cast<const short8*>(&act[m * K + sg * 8]);
        }
    };
    auto loadW = [&](int kk, int slot) {
#pragma unroll
        for (int ns = 0; ns < 4; ns++)
            wreg[slot][ns] = *reinterpret_cast<const short8*>(
                &Wt[wrow[ns] * K + kk * 32 + quad * 8]);
    };

    loadW(0, 0); loadA(0, 0);
    loadW(1, 1); loadA(1, 1);
#pragma unroll
    for (int kk = 0; kk < KK; kk++) {
        int cur = kk & 1;
#pragma unroll
        for (int ms = 0; ms < 4; ms++)
#pragma unroll
            for (int ns = 0; ns < 4; ns++)
                acc[ms][ns] = __builtin_amdgcn_mfma_f32_16x16x32_bf16(
                    wreg[cur][ns], areg[cur][ms], acc[ms][ns], 0, 0, 0);
        if (kk + 2 < KK) { loadW(kk + 2, cur); loadA(kk + 2, cur); }
    }
}

__global__ __launch_bounds__(512, 2) void mlp_kernel(
    const float* __restrict__ objects, const int* __restrict__ seg_ids,
    const short* __restrict__ W1T, const short* __restrict__ W2T,
    const short* __restrict__ W3T,
    const float* __restrict__ b1, const float* __restrict__ b2,
    const float* __restrict__ b3,
    const float* __restrict__ qbuf, float* __restrict__ logits_out,
    short* __restrict__ vout) {
    __shared__ __align__(16) short bufA[128 * 256];   // h1 / logit slots / v-stage
    __shared__ __align__(16) short bufB[128 * 256];   // X (32KB used) / h2

    const int tid  = threadIdx.x;
    const int wave = tid >> 6;
    const int lane = tid & 63;
    const int quad = lane >> 4;
    const int l16  = lane & 15;
    const int wm   = wave & 1;
    const int wn   = wave >> 1;
    const int mbase = wm * 64;
    const int nbase = wn * 64;
    const int row0  = blockIdx.x * 128;

    // ---- stage X: objects[row0..row0+127][0:128] fp32 -> bf16 swizzled (K=128)
    {
        const float4* op = reinterpret_cast<const float4*>(objects + (size_t)row0 * 128);
#pragma unroll
        for (int i = 0; i < 4; i++) {
            int u = tid + i * 512;           // 0..2047: m = u>>4, kgrp = u&15
            int m = u >> 4, kg = u & 15;
            float4 x0 = op[u * 2];
            float4 x1 = op[u * 2 + 1];
            short8 s;
            s[0] = f2bf(x0.x); s[1] = f2bf(x0.y); s[2] = f2bf(x0.z); s[3] = f2bf(x0.w);
            s[4] = f2bf(x1.x); s[5] = f2bf(x1.y); s[6] = f2bf(x1.z); s[7] = f2bf(x1.w);
            *reinterpret_cast<short8*>(&bufB[m * 128 + ((kg ^ (m & 15)) * 8)]) = s;
        }
    }
    __syncthreads();

    f32x4 acc[4][4];

    // epilogue: bias + optional relu -> packed short4 swizzled store (K_out=256)
    auto store_act = [&](short* dst, const float* __restrict__ bias) {
#pragma unroll
        for (int ns = 0; ns < 4; ns++) {
            int n0 = nbase + ns * 16 + quad * 4;
            float4 bv = *reinterpret_cast<const float4*>(&bias[n0]);
#pragma unroll
            for (int ms = 0; ms < 4; ms++) {
                int m = mbase + ms * 16 + l16;
                float v0 = fmaxf(acc[ms][ns][0] + bv.x, 0.f);
                float v1 = fmaxf(acc[ms][ns][1] + bv.y, 0.f);
                float v2 = fmaxf(acc[ms][ns][2] + bv.z, 0.f);
                float v3 = fmaxf(acc[ms][ns][3] + bv.w, 0.f);
                short4 s;
                s.x = f2bf(v0); s.y = f2bf(v1); s.z = f2bf(v2); s.w = f2bf(v3);
                *reinterpret_cast<short4*>(
                    &dst[m * 256 + (((n0 >> 3) ^ (m & 31)) * 8) + (n0 & 7)]) = s;
            }
        }
    };

    // ---- layer 1: h1 = relu(X @ W1 + b1)   -> bufA
    run_layer<128>(bufB, W1T, mbase, nbase, l16, quad, acc);
    store_act(bufA, b1);
    __syncthreads();

    // ---- layer 2: h2 = relu(h1 @ W2 + b2)  -> bufB
    run_layer<256>(bufA, W2T, mbase, nbase, l16, quad, acc);
    store_act(bufB, b2);
    __syncthreads();

    // ---- layer 3 k-half: logits = (h2 @ W3k + b3k) . q[seg] / 16
    run_layer<256>(bufB, W3T, mbase, nbase, l16, quad, acc);
    {
        float* slots = reinterpret_cast<float*>(bufA);   // [4 wn][128 m]
#pragma unroll
        for (int ms = 0; ms < 4; ms++) {
            int m = mbase + ms * 16 + l16;
            int seg = seg_ids[row0 + m];
            const float* qrow = qbuf + (size_t)seg * 256;
            float p = 0.f;
#pragma unroll
            for (int ns = 0; ns < 4; ns++) {
                int n0 = nbase + ns * 16 + quad * 4;
                float4 q4 = *reinterpret_cast<const float4*>(&qrow[n0]);
                float4 b4 = *reinterpret_cast<const float4*>(&b3[n0]);
                p += (acc[ms][ns][0] + b4.x) * q4.x
                   + (acc[ms][ns][1] + b4.y) * q4.y
                   + (acc[ms][ns][2] + b4.z) * q4.z
                   + (acc[ms][ns][3] + b4.w) * q4.w;
            }
            p += __shfl_xor(p, 16);
            p += __shfl_xor(p, 32);
            if (quad == 0) slots[wn * 128 + m] = p;
        }
    }
    __syncthreads();
    if (tid < 128) {
        const float* sl = reinterpret_cast<const float*>(bufA);
        float s = sl[tid] + sl[128 + tid] + sl[256 + tid] + sl[384 + tid];
        logits_out[row0 + tid] = s * 0.0625f;   // / sqrt(256)
    }
    __syncthreads();

    // ---- layer 3 v-half: v = h2 @ W3v + b3v  -> bufA linear -> global
    run_layer<256>(bufB, W3T + 256 * 256, mbase, nbase, l16, quad, acc);
#pragma unroll
    for (int ns = 0; ns < 4; ns++) {
        int n0 = nbase + ns * 16 + quad * 4;
        float4 b4 = *reinterpret_cast<const float4*>(&b3[256 + n0]);
#pragma unroll
        for (int ms = 0; ms < 4; ms++) {
            int m = mbase + ms * 16 + l16;
            short4 s;
            s.x = f2bf(acc[ms][ns][0] + b4.x);
            s.y = f2bf(acc[ms][ns][1] + b4.y);
            s.z = f2bf(acc[ms][ns][2] + b4.z);
            s.w = f2bf(acc[ms][ns][3] + b4.w);
            *reinterpret_cast<short4*>(&bufA[m * 256 + n0]) = s;
        }
    }
    __syncthreads();
    {
        const short8* s8 = reinterpret_cast<const short8*>(bufA);
        short8* g8 = reinterpret_cast<short8*>(vout + (size_t)row0 * 256);
#pragma unroll
        for (int i = 0; i < 8; i++) g8[tid + i * 512] = s8[tid + i * 512];
    }
}

// ---------------------------------------------------------------------------
// Kernel 4: per-segment softmax + weighted sum of v (4-way row-parallel)
// ---------------------------------------------------------------------------
__global__ __launch_bounds__(256) void segment_kernel(
    const float* __restrict__ logits, const short* __restrict__ vbuf,
    const int* __restrict__ seg_ids, float* __restrict__ emb,
    float* __restrict__ wout) {
    const int b = blockIdx.x;
    const int tid = threadIdx.x;
    __shared__ int range[2];
    __shared__ float wred[4];
    __shared__ float slots[4][256];

    if (tid < 2) {
        int target = b + tid;
        int lo = 0, hi = T_TOTAL;
        while (lo < hi) {
            int mid = (lo + hi) >> 1;
            if (seg_ids[mid] < target) lo = mid + 1; else hi = mid;
        }
        range[tid] = lo;
    }
    __syncthreads();
    const int start = range[0], end = range[1];

    // max
    float mx = -1e30f;
    for (int t = start + tid; t < end; t += 256) mx = fmaxf(mx, logits[t]);
#pragma unroll
    for (int off = 32; off >= 1; off >>= 1) mx = fmaxf(mx, __shfl_xor(mx, off));
    if ((tid & 63) == 0) wred[tid >> 6] = mx;
    __syncthreads();
    mx = fmaxf(fmaxf(wred[0], wred[1]), fmaxf(wred[2], wred[3]));
    __syncthreads();

    // sum of exp
    float s = 0.f;
    for (int t = start + tid; t < end; t += 256) s += __expf(logits[t] - mx);
#pragma unroll
    for (int off = 32; off >= 1; off >>= 1) s += __shfl_xor(s, off);
    if ((tid & 63) == 0) wred[tid >> 6] = s;
    __syncthreads();
    float invz = 1.f / (wred[0] + wred[1] + wred[2] + wred[3]);

    // write w
    for (int t = start + tid; t < end; t += 256)
        wout[t] = __expf(logits[t] - mx) * invz;

    // embedding: thread (r = tid>>6) strides rows by 4; cg = tid&63 owns 4 cols
    const int cg = tid & 63, r = tid >> 6;
    float a0 = 0.f, a1 = 0.f, a2 = 0.f, a3 = 0.f;
    for (int t = start + r; t < end; t += 4) {
        float wv = __expf(logits[t] - mx) * invz;
        short4 v4 = *reinterpret_cast<const short4*>(&vbuf[(size_t)t * 256 + cg * 4]);
        a0 += wv * bf2f(v4.x);
        a1 += wv * bf2f(v4.y);
        a2 += wv * bf2f(v4.z);
        a3 += wv * bf2f(v4.w);
    }
    float4 av = {a0, a1, a2, a3};
    *reinterpret_cast<float4*>(&slots[r][cg * 4]) = av;
    __syncthreads();
    emb[(size_t)b * 256 + tid] =
        slots[0][tid] + slots[1][tid] + slots[2][tid] + slots[3][tid];
}

// ---------------------------------------------------------------------------
extern "C" void kernel_launch(void* const* d_in, const int* in_sizes, int n_in,
                              void* d_out, int out_size, void* d_ws, size_t ws_size,
                              hipStream_t stream) {
    const float* objects = (const float*)d_in[0];
    const float* context = (const float*)d_in[1];
    const int*   seg     = (const int*)d_in[2];
    const float* W1 = (const float*)d_in[3];
    const float* b1 = (const float*)d_in[4];
    const float* W2 = (const float*)d_in[5];
    const float* b2 = (const float*)d_in[6];
    const float* W3 = (const float*)d_in[7];
    const float* b3 = (const float*)d_in[8];
    const float* Wq = (const float*)d_in[9];
    const float* bq = (const float*)d_in[10];

    char* ws = (char*)d_ws;
    float* qbuf   = (float*)(ws);                                  // 4 MB
    short* W1T    = (short*)(ws + 4194304);                        // 64 KB
    short* W2T    = (short*)(ws + 4194304 + 65536);                // 128 KB
    short* W3T    = (short*)(ws + 4194304 + 65536 + 131072);       // 256 KB
    float* logits = (float*)(ws + 4194304 + 65536 + 131072 + 262144);          // 1 MB
    short* vbuf   = (short*)(ws + 4194304 + 65536 + 131072 + 262144 + 1048576); // 128 MB

    float* emb  = (float*)d_out;
    float* wout = emb + (size_t)B_SEG * H_DIM;

    convert_weights<<<896, 256, 0, stream>>>(W1, W2, W3, W1T, W2T, W3T);
    q_kernel<<<B_SEG / 16, 256, 0, stream>>>(context, Wq, bq, qbuf);
    mlp_kernel<<<T_TOTAL / 128, 512, 0, stream>>>(objects, seg, W1T, W2T, W3T,
                                                  b1, b2, b3, qbuf, logits, vbuf);
    segment_kernel<<<B_SEG, 256, 0, stream>>>(logits, vbuf, seg, emb, wout);
}

// Round 3
// 511.172 us; speedup vs baseline: 1.2767x; 1.1297x over previous
//
#include <hip/hip_runtime.h>
#include <hip/hip_bf16.h>

#define T_TOTAL 262144
#define B_SEG   4096

typedef __attribute__((ext_vector_type(8))) short short8;
typedef __attribute__((ext_vector_type(4))) float f32x4;

__device__ __forceinline__ short f2bf(float x) {
    __hip_bfloat16 h = __float2bfloat16(x);
    return *reinterpret_cast<short*>(&h);
}
__device__ __forceinline__ float bf2f(short s) {
    unsigned u = ((unsigned)(unsigned short)s) << 16;
    return __uint_as_float(u);
}

// ---------------------------------------------------------------------------
// transpose_weights: W1,W2,W3v (fp32 [K][N]) -> bf16 [N][K] via LDS 64x64 tiles
// grid: 40 blocks x 256 thr. blocks 0-7: W1(2x4), 8-23: W2(4x4), 24-39: W3v(4x4)
// ---------------------------------------------------------------------------
__global__ __launch_bounds__(256) void transpose_weights(
    const float* __restrict__ W1, const float* __restrict__ W2,
    const float* __restrict__ W3,
    short* __restrict__ W1T, short* __restrict__ W2T, short* __restrict__ W3vT) {
    __shared__ float t[64][68];
    const int b = blockIdx.x, tid = threadIdx.x;
    const float* src; short* dst;
    int k0, n0_src, n0_dst, sstride, dstride;
    if (b < 8) {
        int kt = b >> 2, nt = b & 3;
        src = W1; dst = W1T; sstride = 256; dstride = 128;
        k0 = kt * 64; n0_src = nt * 64; n0_dst = nt * 64;
    } else if (b < 24) {
        int id = b - 8, kt = id >> 2, nt = id & 3;
        src = W2; dst = W2T; sstride = 256; dstride = 256;
        k0 = kt * 64; n0_src = nt * 64; n0_dst = nt * 64;
    } else {
        int id = b - 24, kt = id >> 2, nt = id & 3;
        src = W3; dst = W3vT; sstride = 512; dstride = 256;
        k0 = kt * 64; n0_src = 256 + nt * 64; n0_dst = nt * 64;
    }
    // read 64x64 fp32 tile, coalesced
    {
        int r = tid >> 4, c4 = (tid & 15) * 4;
#pragma unroll
        for (int p = 0; p < 4; p++) {
            int k = p * 16 + r;
            float4 v = *reinterpret_cast<const float4*>(&src[(size_t)(k0 + k) * sstride + n0_src + c4]);
            *reinterpret_cast<float4*>(&t[k][c4]) = v;
        }
    }
    __syncthreads();
    // write transposed bf16: thread -> n = tid>>2, kq = tid&3 (16 k each)
    {
        int n = tid >> 2, kq = tid & 3;
        short8 s0, s1;
#pragma unroll
        for (int i = 0; i < 8; i++) s0[i] = f2bf(t[kq * 16 + i][n]);
#pragma unroll
        for (int i = 0; i < 8; i++) s1[i] = f2bf(t[kq * 16 + 8 + i][n]);
        short* o = &dst[(size_t)(n0_dst + n) * dstride + k0 + kq * 16];
        *reinterpret_cast<short8*>(o) = s0;
        *reinterpret_cast<short8*>(o + 8) = s1;
    }
}

// ---------------------------------------------------------------------------
// vec_kernel: bz[j] = W3[j,:256].bq ; wc[c] = Wq[c,:].b3[:256] ; c0 = bq.b3[:256]
// ---------------------------------------------------------------------------
__global__ __launch_bounds__(256) void vec_kernel(
    const float* __restrict__ Wq, const float* __restrict__ W3,
    const float* __restrict__ bq, const float* __restrict__ b3,
    float* __restrict__ bz, float* __restrict__ wc, float* __restrict__ c0) {
    const int tid = threadIdx.x;
    if (blockIdx.x == 0) {
        float s = 0.f;
        for (int n = 0; n < 256; n += 4) {
            float4 a = *reinterpret_cast<const float4*>(&W3[(size_t)tid * 512 + n]);
            float4 b = *reinterpret_cast<const float4*>(&bq[n]);
            s += a.x * b.x + a.y * b.y + a.z * b.z + a.w * b.w;
        }
        bz[tid] = s;
    } else {
#pragma unroll
        for (int h = 0; h < 2; h++) {
            int c = h * 256 + tid;
            float s = 0.f;
            for (int n = 0; n < 256; n += 4) {
                float4 a = *reinterpret_cast<const float4*>(&Wq[(size_t)c * 256 + n]);
                float4 b = *reinterpret_cast<const float4*>(&b3[n]);
                s += a.x * b.x + a.y * b.y + a.z * b.z + a.w * b.w;
            }
            wc[c] = s;
        }
        if (tid == 0) {
            float s = 0.f;
            for (int n = 0; n < 256; n++) s += bq[n] * b3[n];
            c0[0] = s;
        }
    }
}

// ---------------------------------------------------------------------------
// prep_wqz: Wqz[c][j] = sum_n Wq[c][n] * W3[j][n]  (fp32, 512x256)
// 512 blocks: 16c x 16j tile each
// ---------------------------------------------------------------------------
__global__ __launch_bounds__(256) void prep_wqz(
    const float* __restrict__ Wq, const float* __restrict__ W3,
    float* __restrict__ Wqz) {
    __shared__ float wq[16][260];
    __shared__ float w3[16][260];
    const int tid = threadIdx.x;
    const int c0 = (blockIdx.x >> 4) * 16, j0 = (blockIdx.x & 15) * 16;
    {
        int r = tid >> 4, nq = tid & 15;
#pragma unroll
        for (int p = 0; p < 4; p++) {
            int col = nq * 4 + p * 64;
            *reinterpret_cast<float4*>(&wq[r][col]) =
                *reinterpret_cast<const float4*>(&Wq[(size_t)(c0 + r) * 256 + col]);
            *reinterpret_cast<float4*>(&w3[r][col]) =
                *reinterpret_cast<const float4*>(&W3[(size_t)(j0 + r) * 512 + col]);
        }
    }
    __syncthreads();
    const int ci = tid >> 4, ji = tid & 15;
    float s = 0.f;
    for (int n = 0; n < 256; n += 4) {
        float4 a = *reinterpret_cast<const float4*>(&wq[ci][n]);
        float4 b = *reinterpret_cast<const float4*>(&w3[ji][n]);
        s += a.x * b.x + a.y * b.y + a.z * b.z + a.w * b.w;
    }
    Wqz[(size_t)(c0 + ci) * 256 + j0 + ji] = s;
}

// ---------------------------------------------------------------------------
// zq_kernel: ZQ = context @ Wqz + bz  (fp32 [4096][256]); 64x64 tile SGEMM
// grid (64, 4); A staged via LDS (transposed), B read from L2 (broadcast-y)
// ---------------------------------------------------------------------------
__global__ __launch_bounds__(256) void zq_kernel(
    const float* __restrict__ ctx, const float* __restrict__ Wqz,
    const float* __restrict__ bz, float* __restrict__ zq) {
    __shared__ float As[2][16][68];
    const int tid = threadIdx.x;
    const int tm = tid & 15, tn = tid >> 4;
    const int row0 = blockIdx.x * 64, col0 = blockIdx.y * 64;
    const int lr = tid >> 2, lk = tid & 3;

    float acc[4][4];
#pragma unroll
    for (int i = 0; i < 4; i++)
#pragma unroll
        for (int j = 0; j < 4; j++) acc[i][j] = 0.f;

    float4 av = *reinterpret_cast<const float4*>(&ctx[(size_t)(row0 + lr) * 512 + lk * 4]);
    for (int c = 0; c < 32; c++) {
        int cur = c & 1;
        As[cur][lk * 4 + 0][lr] = av.x;
        As[cur][lk * 4 + 1][lr] = av.y;
        As[cur][lk * 4 + 2][lr] = av.z;
        As[cur][lk * 4 + 3][lr] = av.w;
        __syncthreads();
        if (c < 31)
            av = *reinterpret_cast<const float4*>(
                &ctx[(size_t)(row0 + lr) * 512 + (c + 1) * 16 + lk * 4]);
#pragma unroll
        for (int k = 0; k < 16; k++) {
            float4 a = *reinterpret_cast<const float4*>(&As[cur][k][tm * 4]);
            float4 b = *reinterpret_cast<const float4*>(
                &Wqz[(size_t)(c * 16 + k) * 256 + col0 + tn * 4]);
#pragma unroll
            for (int i = 0; i < 4; i++) {
                float ai = (i == 0) ? a.x : (i == 1) ? a.y : (i == 2) ? a.z : a.w;
                acc[i][0] += ai * b.x; acc[i][1] += ai * b.y;
                acc[i][2] += ai * b.z; acc[i][3] += ai * b.w;
            }
        }
    }
    float4 bv = *reinterpret_cast<const float4*>(&bz[col0 + tn * 4]);
#pragma unroll
    for (int i = 0; i < 4; i++) {
        float4 o = {acc[i][0] + bv.x, acc[i][1] + bv.y, acc[i][2] + bv.z, acc[i][3] + bv.w};
        *reinterpret_cast<float4*>(&zq[(size_t)(row0 + tm * 4 + i) * 256 + col0 + tn * 4]) = o;
    }
}

// ---------------------------------------------------------------------------
// cvec_kernel: cbuf[s] = ctx[s,:].wc + c0
// ---------------------------------------------------------------------------
__global__ __launch_bounds__(256) void cvec_kernel(
    const float* __restrict__ ctx, const float* __restrict__ wc,
    const float* __restrict__ c0, float* __restrict__ cbuf) {
    const int tid = threadIdx.x;
    const int row = blockIdx.x * 32 + (tid >> 3);
    const int l = tid & 7;
    float s = 0.f;
    for (int i = 0; i < 64; i += 4) {
        float4 a = *reinterpret_cast<const float4*>(&ctx[(size_t)row * 512 + l * 64 + i]);
        float4 b = *reinterpret_cast<const float4*>(&wc[l * 64 + i]);
        s += a.x * b.x + a.y * b.y + a.z * b.z + a.w * b.w;
    }
    s += __shfl_xor(s, 1); s += __shfl_xor(s, 2); s += __shfl_xor(s, 4);
    if (l == 0) cbuf[row] = s + c0[0];
}

// ---------------------------------------------------------------------------
// mlp_kernel: fused MLP, M=128, 8 waves (2M x 4N), single 64KB act buffer.
// Swizzle (all K): elem(m,k) at m*K + ((k>>3)^(m&15))*8 + (k&7).
// MFMA operand swap: D = W_frag x act_frag -> lane holds 4 consecutive n.
// logits folded into layer-2 epilogue via zq (no k-GEMM).
// ---------------------------------------------------------------------------
template <int K>
__device__ __forceinline__ void run_layer(
    const short* __restrict__ act, const short* __restrict__ Wt,
    int mbase, int nbase, int l16, int quad, f32x4 acc[4][4]) {
    constexpr int KK = K / 32;
    const f32x4 zero = {0.f, 0.f, 0.f, 0.f};
#pragma unroll
    for (int i = 0; i < 4; i++)
#pragma unroll
        for (int j = 0; j < 4; j++) acc[i][j] = zero;

    short8 wreg[2][4], areg[2][4];
    int arow[4], wrow[4];
#pragma unroll
    for (int ms = 0; ms < 4; ms++) arow[ms] = mbase + ms * 16 + l16;
#pragma unroll
    for (int ns = 0; ns < 4; ns++) wrow[ns] = nbase + ns * 16 + l16;

    auto loadA = [&](int kk, int slot) {
#pragma unroll
        for (int ms = 0; ms < 4; ms++) {
            int m = arow[ms];
            int sg = (kk * 4 + quad) ^ (m & 15);
            areg[slot][ms] = *reinterpret_cast<const short8*>(&act[m * K + sg * 8]);
        }
    };
    auto loadW = [&](int kk, int slot) {
#pragma unroll
        for (int ns = 0; ns < 4; ns++)
            wreg[slot][ns] = *reinterpret_cast<const short8*>(
                &Wt[wrow[ns] * K + kk * 32 + quad * 8]);
    };

    loadW(0, 0); loadA(0, 0);
    loadW(1, 1); loadA(1, 1);
#pragma unroll
    for (int kk = 0; kk < KK; kk++) {
        int cur = kk & 1;
#pragma unroll
        for (int ms = 0; ms < 4; ms++)
#pragma unroll
            for (int ns = 0; ns < 4; ns++)
                acc[ms][ns] = __builtin_amdgcn_mfma_f32_16x16x32_bf16(
                    wreg[cur][ns], areg[cur][ms], acc[cur == cur ? ms : ms][ns], 0, 0, 0);
        if (kk + 2 < KK) { loadW(kk + 2, cur); loadA(kk + 2, cur); }
    }
}

__global__ __launch_bounds__(512, 4) void mlp_kernel(
    const float* __restrict__ objects, const int* __restrict__ seg_ids,
    const short* __restrict__ W1T, const short* __restrict__ W2T,
    const short* __restrict__ W3vT,
    const float* __restrict__ b1, const float* __restrict__ b2,
    const float* __restrict__ b3,
    const float* __restrict__ zqbuf, const float* __restrict__ cbuf,
    float* __restrict__ logits_out, short* __restrict__ vout) {
    __shared__ __align__(16) short bufH[128 * 256];   // 64 KB: X -> h1 -> h2 -> v
    __shared__ float slots[4][128];

    const int tid  = threadIdx.x;
    const int wave = tid >> 6;
    const int lane = tid & 63;
    const int quad = lane >> 4;
    const int l16  = lane & 15;
    const int mbase = (wave & 1) * 64;
    const int wn    = wave >> 1;
    const int nbase = wn * 64;
    const int row0  = blockIdx.x * 128;

    // ---- stage X (fp32 -> bf16, K=128 swizzled layout in bufH[0:32KB])
    {
        const float4* op = reinterpret_cast<const float4*>(objects + (size_t)row0 * 128);
#pragma unroll
        for (int i = 0; i < 4; i++) {
            int u = tid + i * 512;           // 0..2047: m = u>>4, kg = u&15
            int m = u >> 4, kg = u & 15;
            float4 x0 = op[u * 2];
            float4 x1 = op[u * 2 + 1];
            short8 s;
            s[0] = f2bf(x0.x); s[1] = f2bf(x0.y); s[2] = f2bf(x0.z); s[3] = f2bf(x0.w);
            s[4] = f2bf(x1.x); s[5] = f2bf(x1.y); s[6] = f2bf(x1.z); s[7] = f2bf(x1.w);
            *reinterpret_cast<short8*>(&bufH[m * 128 + ((kg ^ (m & 15)) * 8)]) = s;
        }
    }
    __syncthreads();

    f32x4 acc[4][4];

    auto store_act = [&](const float* __restrict__ bias) {
#pragma unroll
        for (int ns = 0; ns < 4; ns++) {
            int n0 = nbase + ns * 16 + quad * 4;
            float4 bv = *reinterpret_cast<const float4*>(&bias[n0]);
#pragma unroll
            for (int ms = 0; ms < 4; ms++) {
                int m = mbase + ms * 16 + l16;
                short4 s;
                s.x = f2bf(fmaxf(acc[ms][ns][0] + bv.x, 0.f));
                s.y = f2bf(fmaxf(acc[ms][ns][1] + bv.y, 0.f));
                s.z = f2bf(fmaxf(acc[ms][ns][2] + bv.z, 0.f));
                s.w = f2bf(fmaxf(acc[ms][ns][3] + bv.w, 0.f));
                *reinterpret_cast<short4*>(
                    &bufH[m * 256 + (((n0 >> 3) ^ (m & 15)) * 8) + (n0 & 7)]) = s;
            }
        }
    };

    // ---- layer 1: h1 = relu(X @ W1 + b1)
    run_layer<128>(bufH, W1T, mbase, nbase, l16, quad, acc);
    __syncthreads();                 // X fully consumed
    store_act(b1);
    __syncthreads();

    // ---- layer 2: h2 = relu(h1 @ W2 + b2); fold logits = h2.zq[seg]
    run_layer<256>(bufH, W2T, mbase, nbase, l16, quad, acc);
    __syncthreads();                 // h1 fully consumed
    {
        float part[4] = {0.f, 0.f, 0.f, 0.f};
        int segm[4];
#pragma unroll
        for (int ms = 0; ms < 4; ms++) segm[ms] = seg_ids[row0 + mbase + ms * 16 + l16];
#pragma unroll
        for (int ns = 0; ns < 4; ns++) {
            int n0 = nbase + ns * 16 + quad * 4;
            float4 bv = *reinterpret_cast<const float4*>(&b2[n0]);
#pragma unroll
            for (int ms = 0; ms < 4; ms++) {
                int m = mbase + ms * 16 + l16;
                float h0 = fmaxf(acc[ms][ns][0] + bv.x, 0.f);
                float h1v = fmaxf(acc[ms][ns][1] + bv.y, 0.f);
                float h2v = fmaxf(acc[ms][ns][2] + bv.z, 0.f);
                float h3 = fmaxf(acc[ms][ns][3] + bv.w, 0.f);
                short4 s;
                s.x = f2bf(h0); s.y = f2bf(h1v); s.z = f2bf(h2v); s.w = f2bf(h3);
                *reinterpret_cast<short4*>(
                    &bufH[m * 256 + (((n0 >> 3) ^ (m & 15)) * 8) + (n0 & 7)]) = s;
                float4 zq4 = *reinterpret_cast<const float4*>(
                    &zqbuf[(size_t)segm[ms] * 256 + n0]);
                part[ms] += h0 * zq4.x + h1v * zq4.y + h2v * zq4.z + h3 * zq4.w;
            }
        }
#pragma unroll
        for (int ms = 0; ms < 4; ms++) {
            float p = part[ms];
            p += __shfl_xor(p, 16);
            p += __shfl_xor(p, 32);
            if (quad == 0) slots[wn][mbase + ms * 16 + l16] = p;
        }
    }
    __syncthreads();
    if (tid < 128) {
        int seg = seg_ids[row0 + tid];
        float s = slots[0][tid] + slots[1][tid] + slots[2][tid] + slots[3][tid] + cbuf[seg];
        logits_out[row0 + tid] = s * 0.0625f;   // / sqrt(256)
    }

    // ---- layer 3 v-half: v = h2 @ W3v + b3v
    run_layer<256>(bufH, W3vT, mbase, nbase, l16, quad, acc);
    __syncthreads();                 // h2 fully consumed
#pragma unroll
    for (int ns = 0; ns < 4; ns++) {
        int n0 = nbase + ns * 16 + quad * 4;
        float4 bv = *reinterpret_cast<const float4*>(&b3[256 + n0]);
#pragma unroll
        for (int ms = 0; ms < 4; ms++) {
            int m = mbase + ms * 16 + l16;
            short4 s;
            s.x = f2bf(acc[ms][ns][0] + bv.x);
            s.y = f2bf(acc[ms][ns][1] + bv.y);
            s.z = f2bf(acc[ms][ns][2] + bv.z);
            s.w = f2bf(acc[ms][ns][3] + bv.w);
            *reinterpret_cast<short4*>(
                &bufH[m * 256 + (((n0 >> 3) ^ (m & 15)) * 8) + (n0 & 7)]) = s;
        }
    }
    __syncthreads();
    // copy out, un-swizzling
#pragma unroll
    for (int i = 0; i < 8; i++) {
        int idx = tid + i * 512;          // [0,4096): m = idx>>5, sg = idx&31
        int m = idx >> 5, sg = idx & 31;
        short8 val = *reinterpret_cast<const short8*>(&bufH[m * 256 + sg * 8]);
        int n0 = (sg ^ (m & 15)) * 8;
        *reinterpret_cast<short8*>(&vout[(size_t)(row0 + m) * 256 + n0]) = val;
    }
}

// ---------------------------------------------------------------------------
// segment_kernel: per-segment softmax + weighted sum of v
// ---------------------------------------------------------------------------
__global__ __launch_bounds__(256) void segment_kernel(
    const float* __restrict__ logits, const short* __restrict__ vbuf,
    const int* __restrict__ seg_ids, float* __restrict__ emb,
    float* __restrict__ wout) {
    const int b = blockIdx.x;
    const int tid = threadIdx.x;
    __shared__ int range[2];
    __shared__ float wred[4];
    __shared__ float slots[4][256];

    if (tid < 2) {
        int target = b + tid;
        int lo = 0, hi = T_TOTAL;
        while (lo < hi) {
            int mid = (lo + hi) >> 1;
            if (seg_ids[mid] < target) lo = mid + 1; else hi = mid;
        }
        range[tid] = lo;
    }
    __syncthreads();
    const int start = range[0], end = range[1];

    float mx = -1e30f;
    for (int t = start + tid; t < end; t += 256) mx = fmaxf(mx, logits[t]);
#pragma unroll
    for (int off = 32; off >= 1; off >>= 1) mx = fmaxf(mx, __shfl_xor(mx, off));
    if ((tid & 63) == 0) wred[tid >> 6] = mx;
    __syncthreads();
    mx = fmaxf(fmaxf(wred[0], wred[1]), fmaxf(wred[2], wred[3]));
    __syncthreads();

    float s = 0.f;
    for (int t = start + tid; t < end; t += 256) s += __expf(logits[t] - mx);
#pragma unroll
    for (int off = 32; off >= 1; off >>= 1) s += __shfl_xor(s, off);
    if ((tid & 63) == 0) wred[tid >> 6] = s;
    __syncthreads();
    float invz = 1.f / (wred[0] + wred[1] + wred[2] + wred[3]);

    for (int t = start + tid; t < end; t += 256)
        wout[t] = __expf(logits[t] - mx) * invz;

    const int cg = tid & 63, r = tid >> 6;
    float a0 = 0.f, a1 = 0.f, a2 = 0.f, a3 = 0.f;
    for (int t = start + r; t < end; t += 4) {
        float wv = __expf(logits[t] - mx) * invz;
        short4 v4 = *reinterpret_cast<const short4*>(&vbuf[(size_t)t * 256 + cg * 4]);
        a0 += wv * bf2f(v4.x);
        a1 += wv * bf2f(v4.y);
        a2 += wv * bf2f(v4.z);
        a3 += wv * bf2f(v4.w);
    }
    float4 av = {a0, a1, a2, a3};
    *reinterpret_cast<float4*>(&slots[r][cg * 4]) = av;
    __syncthreads();
    emb[(size_t)b * 256 + tid] =
        slots[0][tid] + slots[1][tid] + slots[2][tid] + slots[3][tid];
}

// ---------------------------------------------------------------------------
extern "C" void kernel_launch(void* const* d_in, const int* in_sizes, int n_in,
                              void* d_out, int out_size, void* d_ws, size_t ws_size,
                              hipStream_t stream) {
    const float* objects = (const float*)d_in[0];
    const float* context = (const float*)d_in[1];
    const int*   seg     = (const int*)d_in[2];
    const float* W1 = (const float*)d_in[3];
    const float* b1 = (const float*)d_in[4];
    const float* W2 = (const float*)d_in[5];
    const float* b2 = (const float*)d_in[6];
    const float* W3 = (const float*)d_in[7];
    const float* b3 = (const float*)d_in[8];
    const float* Wq = (const float*)d_in[9];
    const float* bq = (const float*)d_in[10];

    char* ws = (char*)d_ws;
    float* zqbuf = (float*)(ws);                        // 4 MB
    float* cbuf  = (float*)(ws + 4194304);              // 16 KB
    short* W1T   = (short*)(ws + 4210688);              // 64 KB
    short* W2T   = (short*)(ws + 4276224);              // 128 KB
    short* W3vT  = (short*)(ws + 4407296);              // 128 KB
    // logits region (1 MB) doubles as scratch for Wqz/bz/wc/c0 (consumed
    // before mlp_kernel writes logits over it)
    char*  lreg   = ws + 4538368;
    float* logits = (float*)lreg;
    float* Wqz    = (float*)lreg;                       // 512 KB
    float* bz     = (float*)(lreg + 524288);            // 1 KB
    float* wc     = (float*)(lreg + 525312);            // 2 KB
    float* c0     = (float*)(lreg + 527360);            // 16 B
    short* vbuf   = (short*)(ws + 5586944);             // 128 MB

    float* emb  = (float*)d_out;
    float* wout = emb + (size_t)B_SEG * 256;

    transpose_weights<<<40, 256, 0, stream>>>(W1, W2, W3, W1T, W2T, W3vT);
    vec_kernel<<<2, 256, 0, stream>>>(Wq, W3, bq, b3, bz, wc, c0);
    prep_wqz<<<512, 256, 0, stream>>>(Wq, W3, Wqz);
    zq_kernel<<<dim3(64, 4), 256, 0, stream>>>(context, Wqz, bz, zqbuf);
    cvec_kernel<<<128, 256, 0, stream>>>(context, wc, c0, cbuf);
    mlp_kernel<<<T_TOTAL / 128, 512, 0, stream>>>(objects, seg, W1T, W2T, W3vT,
                                                  b1, b2, b3, zqbuf, cbuf,
                                                  logits, vbuf);
    segment_kernel<<<B_SEG, 256, 0, stream>>>(logits, vbuf, seg, emb, wout);
}